// Round 2
// baseline (343.083 us; speedup 1.0000x reference)
//
#include <hip/hip_runtime.h>

// MHA: B=4, S=2048, HID=1024, H=16, D=64. fp32 in/out, bf16 MFMA internally.
// R6: attn VALU diet + occupancy.
//   - v_cvt_pk_bf16_f32 (1 op) replaces pk2f (3 ops) in the softmax hot path
//   - denominator via ones-row MFMA (den = 1^T @ P): kills 32 VALU adds/tile
//     AND the final cross-lane reduce (C/D col = lane&31 = q -> den is
//     lane-local in dacc[0])
//   - sacc restructured to per-t lifetime (peak VGPR ~110)
//   - __launch_bounds__(256,4): 4 blocks/CU (16 waves), was 2
//
// ws layout (u16 elems):
//   qb/Ob : 0         (converted q, scaled by log2e/8; reused for attn out)
//   kb    : 8388608
//   vb    : 16777216
//   Qb    : 25165824  [BH][S][64]
//   Kb    : 33554432  [BH][S][64]
//   Vt    : 41943040  [BH][64][S]
//   Wt    : 50331648  4x [N=1024][K=1024] bf16 (Wq,Wk,Wv,Wo transposed)

typedef __attribute__((ext_vector_type(8))) short short8;
typedef __attribute__((ext_vector_type(4))) float float4v;
typedef __attribute__((ext_vector_type(16))) float float16v;
typedef __attribute__((ext_vector_type(2))) unsigned int uint2v;

#if __has_builtin(__builtin_amdgcn_exp2f)
#define EXP2F(x) __builtin_amdgcn_exp2f(x)
#else
#define EXP2F(x) exp2f(x)
#endif

// round-half-up bf16 (tie-only deviation from RNE, <=1 ulp): 2 ops
__device__ __forceinline__ unsigned short f2b(float x) {
  return (unsigned short)((__float_as_uint(x) + 0x8000u) >> 16);
}
// pack two floats -> two bf16 in 3 VALU (add, add, v_perm). low16 = a.
__device__ __forceinline__ unsigned pk2f(float a, float b) {
  unsigned ua = __float_as_uint(a) + 0x8000u;
  unsigned ub = __float_as_uint(b) + 0x8000u;
  return __builtin_amdgcn_perm(ub, ua, 0x07060302);
}
// pack two floats -> two bf16 in ONE VALU (RNE). low16 = a.
__device__ __forceinline__ unsigned cvtpk(float a, float b) {
  unsigned r;
  asm("v_cvt_pk_bf16_f32 %0, %1, %2" : "=v"(r) : "v"(a), "v"(b));
  return r;
}

// async global->LDS, 16B per lane (dest = wave-uniform base + lane*16).
typedef __attribute__((address_space(3))) unsigned int lds_uint;
typedef const __attribute__((address_space(1))) unsigned int gbl_uint;
__device__ __forceinline__ void stage16(const unsigned short* g, unsigned short* l) {
#if __has_builtin(__builtin_amdgcn_global_load_lds)
  __builtin_amdgcn_global_load_lds((gbl_uint*)g, (lds_uint*)l, 16, 0, 0);
#else
  *(uint4*)l = *(const uint4*)g;
#endif
}

// ---------------- conversion kernels ----------------
__global__ __launch_bounds__(256) void conv_qkv(const float* __restrict__ q,
                                                const float* __restrict__ k,
                                                const float* __restrict__ v,
                                                unsigned short* __restrict__ ws,
                                                float qscale) {
  const int z = blockIdx.y;
  const float* src = z == 0 ? q : (z == 1 ? k : v);
  unsigned short* dst = ws + (size_t)z * 8388608;
  const float s = z == 0 ? qscale : 1.0f;
  size_t i = ((size_t)blockIdx.x * 256 + threadIdx.x) * 8;
  float4v a = *(const float4v*)(src + i);
  float4v b = *(const float4v*)(src + i + 4);
  uint4 o;
  o.x = pk2f(a.x * s, a.y * s);
  o.y = pk2f(a.z * s, a.w * s);
  o.z = pk2f(b.x * s, b.y * s);
  o.w = pk2f(b.z * s, b.w * s);
  *(uint4*)(dst + i) = o;
}

// W [K][N] fp32 -> Wt [N][K] bf16, LDS 32x33 tile transpose. 4 matrices (z).
__global__ __launch_bounds__(256) void wtrans(const float* __restrict__ Wq,
                                              const float* __restrict__ Wk,
                                              const float* __restrict__ Wv,
                                              const float* __restrict__ Wo,
                                              unsigned short* __restrict__ Wt) {
  __shared__ float tile[32][33];
  const float* W = blockIdx.z == 0 ? Wq : blockIdx.z == 1 ? Wk
                   : blockIdx.z == 2 ? Wv : Wo;
  unsigned short* T = Wt + (size_t)blockIdx.z * 1048576;
  const int tx = threadIdx.x & 31, ty = threadIdx.x >> 5;
  const int k0 = blockIdx.y * 32, n0 = blockIdx.x * 32;
#pragma unroll
  for (int i = 0; i < 4; i++)
    tile[ty + 8 * i][tx] = W[(size_t)(k0 + ty + 8 * i) * 1024 + n0 + tx];
  __syncthreads();
#pragma unroll
  for (int i = 0; i < 4; i++)
    T[(size_t)(n0 + ty + 8 * i) * 1024 + k0 + tx] = f2b(tile[tx][ty + 8 * i]);
}

// ---------------- GEMM: C = A(8192x1024) @ Bt^T, bf16 ----------------
// Grid = 512 linear blocks. XCD swizzle: A-tile(m) sharers (all 8 n) get ids
// congruent mod 8 -> same XCD (round-robin dispatch) -> A served from L2.
// MODE 0 (SWAP): bf16 out [(b*16+h)*2048+s][64]; MODE 1: bf16 [(bh)*64+d][2048]
// (V^T); MODE 2: fp32 [tok][1024].
template <int MODE, bool SWAP>
__global__ __launch_bounds__(256, 2) void gemm_bt(const unsigned short* __restrict__ A,
                                                  const unsigned short* __restrict__ Bt,
                                                  void* __restrict__ Cg) {
  __shared__ __align__(16) unsigned short As[128 * 64];
  __shared__ __align__(16) unsigned short Bs[128 * 64];
  const int tid = threadIdx.x;
  const int lane = tid & 63;
  const int w = tid >> 6;
  const int quad = lane >> 4, col = lane & 15;
  const int wm = w >> 1, wn = w & 1;
  // XCD swizzle: lin = grp*8 + xcd; m_tile = (grp&7)*8 + xcd; n_tile = grp>>3
  const int lin = blockIdx.x;
  const int xcd = lin & 7, grp = lin >> 3;
  const int m0 = ((grp & 7) * 8 + xcd) * 128;
  const int n0 = (grp >> 3) * 128;
  const int rA = lane >> 3, cA = lane & 7;

  float4v acc[4][4] = {};  // SWAP: [ni][mi]; else [mi][ni]

  for (int k0 = 0; k0 < 1024; k0 += 64) {
    __syncthreads();
#pragma unroll
    for (int j = 0; j < 4; j++) {
      const int row = w * 32 + j * 8 + rA;  // row&7 == rA
      stage16(A + (unsigned)(m0 + row) * 1024 + k0 + ((cA ^ rA) * 8),
              &As[row * 64 + cA * 8]);
      stage16(Bt + (unsigned)(n0 + row) * 1024 + k0 + ((cA ^ rA) * 8),
              &Bs[row * 64 + cA * 8]);
    }
    __syncthreads();

#pragma unroll
    for (int ks = 0; ks < 2; ks++) {
      short8 af[4], bf[4];
#pragma unroll
      for (int mi = 0; mi < 4; mi++) {
        int row = wm * 64 + mi * 16 + col;
        af[mi] = *(const short8*)&As[row * 64 + (((ks * 4 + quad) ^ (col & 7)) * 8)];
      }
#pragma unroll
      for (int ni = 0; ni < 4; ni++) {
        int row = wn * 64 + ni * 16 + col;
        bf[ni] = *(const short8*)&Bs[row * 64 + (((ks * 4 + quad) ^ (col & 7)) * 8)];
      }
#pragma unroll
      for (int mi = 0; mi < 4; mi++)
#pragma unroll
        for (int ni = 0; ni < 4; ni++) {
          if (SWAP)
            acc[ni][mi] = __builtin_amdgcn_mfma_f32_16x16x32_bf16(
                bf[ni], af[mi], acc[ni][mi], 0, 0, 0);
          else
            acc[mi][ni] = __builtin_amdgcn_mfma_f32_16x16x32_bf16(
                af[mi], bf[ni], acc[mi][ni], 0, 0, 0);
        }
    }
  }

  if (MODE == 0) {  // SWAP: rows(quad*4+r)=hidden, cols(lane)=token
#pragma unroll
    for (int ni = 0; ni < 4; ni++) {
      const int cg = n0 + wn * 64 + ni * 16 + quad * 4;
      const int h = cg >> 6, dlo = cg & 63;
#pragma unroll
      for (int mi = 0; mi < 4; mi++) {
        const int tok = m0 + wm * 64 + mi * 16 + col;
        const int b = tok >> 11, s = tok & 2047;
        uint2 pk;
        pk.x = pk2f(acc[ni][mi][0], acc[ni][mi][1]);
        pk.y = pk2f(acc[ni][mi][2], acc[ni][mi][3]);
        *(uint2*)((unsigned short*)Cg +
                  ((unsigned)((b * 16 + h) * 2048 + s) * 64 + dlo)) = pk;
      }
    }
  } else if (MODE == 1) {  // rows(quad*4+r)=token(consec s), cols(lane)=hidden
#pragma unroll
    for (int mi = 0; mi < 4; mi++) {
      const int tok = m0 + wm * 64 + mi * 16 + quad * 4;
      const int b = tok >> 11, s = tok & 2047;
#pragma unroll
      for (int ni = 0; ni < 4; ni++) {
        const int cg = n0 + wn * 64 + ni * 16 + col;
        const int h = cg >> 6, d = cg & 63;
        uint2 pk;
        pk.x = pk2f(acc[mi][ni][0], acc[mi][ni][1]);
        pk.y = pk2f(acc[mi][ni][2], acc[mi][ni][3]);
        *(uint2*)((unsigned short*)Cg +
                  ((unsigned)((b * 16 + h) * 64 + d) * 2048 + s)) = pk;
      }
    }
  } else {  // fp32 [tok][1024], coalesced
#pragma unroll
    for (int mi = 0; mi < 4; mi++) {
      const int row = m0 + wm * 64 + mi * 16 + quad * 4;
#pragma unroll
      for (int ni = 0; ni < 4; ni++) {
        const int cg = n0 + wn * 64 + ni * 16 + col;
#pragma unroll
        for (int r = 0; r < 4; r++)
          ((float*)Cg)[(unsigned)(row + r) * 1024 + cg] = acc[mi][ni][r];
      }
    }
  }
}

// ---------------- attention (32x32 swapped, in-register softmax) ----------------
// Grid = 1024 linear blocks; swizzle puts the 16 q-blocks of a head on one XCD
// (K/V stream served from L2). 4 waves x 32 q-rows = 128 q / block; KVBLK=64.
// Streaming softmax (no max subtraction), Q pre-scaled by log2e/8 so
// P = exp2(K@Q^T). Per KV tile:
//   S^T[k][q] = mfma_32x32x16(K_frag, Q_frag): lane holds q=lane&31, 16 k-rows
//     per t at row = (r&3)+8*(r>>2)+4*hi  [verified C/D layout]
//   P -> bf16 B-fragments IN REGISTER: v_cvt_pk_bf16_f32 + permlane32_swap
//     (swap(P0,P2) -> words 0,2; swap(P1,P3) -> words 1,3)
//   O^T[d][q] += mfma_32x32x16(V^T_frag, P_frag): C cols = q -> den scale is
//     lane-local; rows = d in packable quads.
//   den[q] += mfma_32x32x16(ones, P_frag): 1^T@P on the MFMA pipe; C/D layout
//     puts den[q] in every lane's dacc[0] -> no cross-lane reduce, no VALU adds.
// K_lds/V_lds double-buffered, stage(kt+1) issued before compute(kt),
// single __syncthreads per tile (vmcnt drain covers staged loads).
__global__ __launch_bounds__(256, 4) void attn_kernel(
    const unsigned short* __restrict__ Qb, const unsigned short* __restrict__ Kb,
    const unsigned short* __restrict__ Vt, unsigned short* __restrict__ Ob) {
  __shared__ __align__(16) unsigned short K_lds[2][64 * 64];  // [s][d] sw8
  __shared__ __align__(16) unsigned short V_lds[2][64 * 64];  // [d][s] sw8

  const int tid = threadIdx.x;
  const int lane = tid & 63;
  const int w = tid >> 6;
  const int l5 = lane & 31, hi = lane >> 5;

  // swizzle: bh = ((lin>>3)&7)*8 + (lin&7), qt = lin>>6  (16 q-tiles of 128)
  const int lin = blockIdx.x;
  const int bh = ((lin >> 3) & 7) * 8 + (lin & 7);
  const int qt = lin >> 6;

  const unsigned short* Kbase = Kb + (size_t)bh * (2048 * 64);
  const unsigned short* Vbase = Vt + (size_t)bh * (64 * 2048);
  const int q0 = qt * 128 + w * 32;

  // Q B-fragments (held in regs): lane q = l5, d = c*16 + hi*8 + j
  short8 qf[4];
#pragma unroll
  for (int c = 0; c < 4; c++)
    qf[c] = *(const short8*)(Qb + ((size_t)bh * 2048 + q0 + l5) * 64 + c * 16 + hi * 8);

  // ones A-fragment for the denominator MFMA (bf16 1.0 = 0x3F80)
  short8 onef;
#pragma unroll
  for (int j = 0; j < 8; j++) onef[j] = (short)0x3F80;

  float16v oacc[2] = {};  // O^T tiles: [dt] rows=d-local, cols=q
  float16v dacc = {};     // den[q] (all 16 rows identical)

  const int sr = lane >> 3, sc = lane & 7;

  // stage K/V tile kt into buffer b: row&7 == sr -> swizzle chunk = sc^sr.
  // LDS dest is lane-linear (base + lane*16B) as global_load_lds requires.
  auto STAGE = [&](int b, int kt) {
    const int s0 = kt * 64;
#pragma unroll
    for (int j = 0; j < 2; j++) {
      const int row = w * 16 + j * 8 + sr;
      stage16(Kbase + (unsigned)(s0 + row) * 64 + ((sc ^ sr) * 8),
              &K_lds[b][row * 64 + sc * 8]);
      stage16(Vbase + (unsigned)row * 2048 + s0 + ((sc ^ sr) * 8),
              &V_lds[b][row * 64 + sc * 8]);
    }
  };

  STAGE(0, 0);
  __syncthreads();

  int cur = 0;
  for (int kt = 0; kt < 32; kt++) {
    if (kt < 31) STAGE(cur ^ 1, kt + 1);  // issue early; drains at barrier

    const unsigned short* Kl = &K_lds[cur][0];
    const unsigned short* Vl = &V_lds[cur][0];

    short8 pf[4];  // pf[kc]: B[k = kc*16 + hi*8 + j][q = l5]
#pragma unroll
    for (int t = 0; t < 2; t++) {
      // --- S^T = K @ Q^T for this 32-k slab ---
      float16v sacc = {};
      __builtin_amdgcn_s_setprio(1);
#pragma unroll
      for (int c = 0; c < 4; c++) {
        short8 kf = *(const short8*)&Kl[(t * 32 + l5) * 64 +
                                        (((c * 2 + hi) ^ (l5 & 7)) * 8)];
        sacc = __builtin_amdgcn_mfma_f32_32x32x16_bf16(kf, qf[c], sacc, 0, 0, 0);
      }
      __builtin_amdgcn_s_setprio(0);

      // --- P = exp2(S^T); cvt_pk + permlane into PV B-fragments ---
#pragma unroll
      for (int half = 0; half < 2; half++) {
        const int k0 = half * 8;
        unsigned P0 = cvtpk(EXP2F(sacc[k0 + 0]), EXP2F(sacc[k0 + 1]));
        unsigned P1 = cvtpk(EXP2F(sacc[k0 + 2]), EXP2F(sacc[k0 + 3]));
        unsigned P2 = cvtpk(EXP2F(sacc[k0 + 4]), EXP2F(sacc[k0 + 5]));
        unsigned P3 = cvtpk(EXP2F(sacc[k0 + 6]), EXP2F(sacc[k0 + 7]));
        unsigned u0, u1, u2, u3;
#if __has_builtin(__builtin_amdgcn_permlane32_swap)
        uint2v a02 = __builtin_amdgcn_permlane32_swap(P0, P2, false, false);
        uint2v a13 = __builtin_amdgcn_permlane32_swap(P1, P3, false, false);
        u0 = a02[0]; u2 = a02[1];
        u1 = a13[0]; u3 = a13[1];
#else
        unsigned p0s = __shfl_xor((int)P0, 32), p2s = __shfl_xor((int)P2, 32);
        unsigned p1s = __shfl_xor((int)P1, 32), p3s = __shfl_xor((int)P3, 32);
        u0 = hi ? p2s : P0; u2 = hi ? P2 : p0s;
        u1 = hi ? p3s : P1; u3 = hi ? P3 : p1s;
#endif
        union { unsigned u[4]; short8 s; } cv;
        cv.u[0] = u0; cv.u[1] = u1; cv.u[2] = u2; cv.u[3] = u3;
        pf[t * 2 + half] = cv.s;
      }
    }

    // --- O^T += V^T @ P (2 d-tiles x 4 k-chunks) and den += 1^T @ P ---
    __builtin_amdgcn_s_setprio(1);
#pragma unroll
    for (int dt = 0; dt < 2; dt++)
#pragma unroll
      for (int kc = 0; kc < 4; kc++) {
        short8 vf = *(const short8*)&Vl[(dt * 32 + l5) * 64 +
                                        (((kc * 2 + hi) ^ (l5 & 7)) * 8)];
        oacc[dt] = __builtin_amdgcn_mfma_f32_32x32x16_bf16(vf, pf[kc], oacc[dt], 0, 0, 0);
      }
#pragma unroll
    for (int kc = 0; kc < 4; kc++)
      dacc = __builtin_amdgcn_mfma_f32_32x32x16_bf16(onef, pf[kc], dacc, 0, 0, 0);
    __builtin_amdgcn_s_setprio(0);

    __syncthreads();  // drains staged loads for kt+1; guards buffer reuse
    cur ^= 1;
  }

  // --- dacc rows all identical = den[q=l5]; lane-local reciprocal ---
  const float rd = 1.f / dacc[0];

  // --- O / den -> Ob [B][S][1024] bf16; reg quads = 4 consecutive d ---
  const int b = bh >> 4, h = bh & 15;
  const unsigned obase = (unsigned)(b * 2048 + q0 + l5) * 1024 + h * 64;
#pragma unroll
  for (int dt = 0; dt < 2; dt++)
#pragma unroll
    for (int g = 0; g < 4; g++) {
      uint2 pk;
      pk.x = cvtpk(oacc[dt][4 * g + 0] * rd, oacc[dt][4 * g + 1] * rd);
      pk.y = cvtpk(oacc[dt][4 * g + 2] * rd, oacc[dt][4 * g + 3] * rd);
      *(uint2*)(Ob + obase + dt * 32 + 8 * g + 4 * hi) = pk;
    }
}

extern "C" void kernel_launch(void* const* d_in, const int* in_sizes, int n_in,
                              void* d_out, int out_size, void* d_ws, size_t ws_size,
                              hipStream_t stream) {
  const float* q = (const float*)d_in[0];
  const float* k = (const float*)d_in[1];
  const float* v = (const float*)d_in[2];
  const float* Wq = (const float*)d_in[3];
  const float* Wk = (const float*)d_in[4];
  const float* Wv = (const float*)d_in[5];
  const float* Wo = (const float*)d_in[6];

  unsigned short* ws = (unsigned short*)d_ws;
  unsigned short* qb = ws;  // reused as Ob after attention
  unsigned short* kb = ws + 8388608;
  unsigned short* vb = ws + 16777216;
  unsigned short* Qb = ws + 25165824;
  unsigned short* Kb = ws + 33554432;
  unsigned short* Vt = ws + 41943040;
  unsigned short* Wt = ws + 50331648;

  dim3 blk(256);
  const float qscale = 0.18033688011112042f;  // log2(e) / sqrt(64)

  conv_qkv<<<dim3(4096, 3), blk, 0, stream>>>(q, k, v, ws, qscale);
  wtrans<<<dim3(32, 32, 4), blk, 0, stream>>>(Wq, Wk, Wv, Wo, Wt);

  gemm_bt<0, true><<<dim3(512), blk, 0, stream>>>(qb, Wt + 0 * 1048576, Qb);
  gemm_bt<0, true><<<dim3(512), blk, 0, stream>>>(kb, Wt + 1 * 1048576, Kb);
  gemm_bt<1, false><<<dim3(512), blk, 0, stream>>>(vb, Wt + 2 * 1048576, Vt);

  attn_kernel<<<dim3(1024), blk, 0, stream>>>(Qb, Kb, Vt, qb /*Ob*/);

  gemm_bt<2, false><<<dim3(512), blk, 0, stream>>>(qb /*Ob*/, Wt + 3 * 1048576,
                                                   (float*)d_out);
}

// Round 3
// 339.366 us; speedup vs baseline: 1.0110x; 1.0110x over previous
//
#include <hip/hip_runtime.h>

// MHA: B=4, S=2048, HID=1024, H=16, D=64. fp32 in/out, bf16 MFMA internally.
// R7: GEMM K-loop converted to stage-early double-buffer (the T3-minimum
// schedule already proven in attn R5): STAGE(next tile) issued BEFORE the
// current tile's MFMAs, one __syncthreads per K-step. LDS 32->64KB (still
// 2 blocks/CU). attn unchanged from R6.
//
// ws layout (u16 elems):
//   qb/Ob : 0         (converted q, scaled by log2e/8; reused for attn out)
//   kb    : 8388608
//   vb    : 16777216
//   Qb    : 25165824  [BH][S][64]
//   Kb    : 33554432  [BH][S][64]
//   Vt    : 41943040  [BH][64][S]
//   Wt    : 50331648  4x [N=1024][K=1024] bf16 (Wq,Wk,Wv,Wo transposed)

typedef __attribute__((ext_vector_type(8))) short short8;
typedef __attribute__((ext_vector_type(4))) float float4v;
typedef __attribute__((ext_vector_type(16))) float float16v;
typedef __attribute__((ext_vector_type(2))) unsigned int uint2v;

#if __has_builtin(__builtin_amdgcn_exp2f)
#define EXP2F(x) __builtin_amdgcn_exp2f(x)
#else
#define EXP2F(x) exp2f(x)
#endif

// round-half-up bf16 (tie-only deviation from RNE, <=1 ulp): 2 ops
__device__ __forceinline__ unsigned short f2b(float x) {
  return (unsigned short)((__float_as_uint(x) + 0x8000u) >> 16);
}
// pack two floats -> two bf16 in 3 VALU (add, add, v_perm). low16 = a.
__device__ __forceinline__ unsigned pk2f(float a, float b) {
  unsigned ua = __float_as_uint(a) + 0x8000u;
  unsigned ub = __float_as_uint(b) + 0x8000u;
  return __builtin_amdgcn_perm(ub, ua, 0x07060302);
}
// pack two floats -> two bf16 in ONE VALU (RNE). low16 = a.
__device__ __forceinline__ unsigned cvtpk(float a, float b) {
  unsigned r;
  asm("v_cvt_pk_bf16_f32 %0, %1, %2" : "=v"(r) : "v"(a), "v"(b));
  return r;
}

// async global->LDS, 16B per lane (dest = wave-uniform base + lane*16).
typedef __attribute__((address_space(3))) unsigned int lds_uint;
typedef const __attribute__((address_space(1))) unsigned int gbl_uint;
__device__ __forceinline__ void stage16(const unsigned short* g, unsigned short* l) {
#if __has_builtin(__builtin_amdgcn_global_load_lds)
  __builtin_amdgcn_global_load_lds((gbl_uint*)g, (lds_uint*)l, 16, 0, 0);
#else
  *(uint4*)l = *(const uint4*)g;
#endif
}

// ---------------- conversion kernels ----------------
__global__ __launch_bounds__(256) void conv_qkv(const float* __restrict__ q,
                                                const float* __restrict__ k,
                                                const float* __restrict__ v,
                                                unsigned short* __restrict__ ws,
                                                float qscale) {
  const int z = blockIdx.y;
  const float* src = z == 0 ? q : (z == 1 ? k : v);
  unsigned short* dst = ws + (size_t)z * 8388608;
  const float s = z == 0 ? qscale : 1.0f;
  size_t i = ((size_t)blockIdx.x * 256 + threadIdx.x) * 8;
  float4v a = *(const float4v*)(src + i);
  float4v b = *(const float4v*)(src + i + 4);
  uint4 o;
  o.x = pk2f(a.x * s, a.y * s);
  o.y = pk2f(a.z * s, a.w * s);
  o.z = pk2f(b.x * s, b.y * s);
  o.w = pk2f(b.z * s, b.w * s);
  *(uint4*)(dst + i) = o;
}

// W [K][N] fp32 -> Wt [N][K] bf16, LDS 32x33 tile transpose. 4 matrices (z).
__global__ __launch_bounds__(256) void wtrans(const float* __restrict__ Wq,
                                              const float* __restrict__ Wk,
                                              const float* __restrict__ Wv,
                                              const float* __restrict__ Wo,
                                              unsigned short* __restrict__ Wt) {
  __shared__ float tile[32][33];
  const float* W = blockIdx.z == 0 ? Wq : blockIdx.z == 1 ? Wk
                   : blockIdx.z == 2 ? Wv : Wo;
  unsigned short* T = Wt + (size_t)blockIdx.z * 1048576;
  const int tx = threadIdx.x & 31, ty = threadIdx.x >> 5;
  const int k0 = blockIdx.y * 32, n0 = blockIdx.x * 32;
#pragma unroll
  for (int i = 0; i < 4; i++)
    tile[ty + 8 * i][tx] = W[(size_t)(k0 + ty + 8 * i) * 1024 + n0 + tx];
  __syncthreads();
#pragma unroll
  for (int i = 0; i < 4; i++)
    T[(size_t)(n0 + ty + 8 * i) * 1024 + k0 + tx] = f2b(tile[tx][ty + 8 * i]);
}

// ---------------- GEMM: C = A(8192x1024) @ Bt^T, bf16 ----------------
// Grid = 512 linear blocks. XCD swizzle: A-tile(m) sharers (all 8 n) get ids
// congruent mod 8 -> same XCD (round-robin dispatch) -> A served from L2.
// Stage-early double-buffered K-loop: STAGE(kt+1) issued before compute(kt),
// single __syncthreads per K-step (drains in-flight global_load_lds + guards
// buffer reuse) -- same schedule as attn_kernel, verified there.
// MODE 0 (SWAP): bf16 out [(b*16+h)*2048+s][64]; MODE 1: bf16 [(bh)*64+d][2048]
// (V^T); MODE 2: fp32 [tok][1024].
template <int MODE, bool SWAP>
__global__ __launch_bounds__(256, 2) void gemm_bt(const unsigned short* __restrict__ A,
                                                  const unsigned short* __restrict__ Bt,
                                                  void* __restrict__ Cg) {
  __shared__ __align__(16) unsigned short As[2][128 * 64];
  __shared__ __align__(16) unsigned short Bs[2][128 * 64];
  const int tid = threadIdx.x;
  const int lane = tid & 63;
  const int w = tid >> 6;
  const int quad = lane >> 4, col = lane & 15;
  const int wm = w >> 1, wn = w & 1;
  // XCD swizzle: lin = grp*8 + xcd; m_tile = (grp&7)*8 + xcd; n_tile = grp>>3
  const int lin = blockIdx.x;
  const int xcd = lin & 7, grp = lin >> 3;
  const int m0 = ((grp & 7) * 8 + xcd) * 128;
  const int n0 = (grp >> 3) * 128;
  const int rA = lane >> 3, cA = lane & 7;

  float4v acc[4][4] = {};  // SWAP: [ni][mi]; else [mi][ni]

  // stage K-chunk k0 into buffer b (dest lane-linear: lane*16B per wave)
  auto STAGE = [&](int b, int k0) {
#pragma unroll
    for (int j = 0; j < 4; j++) {
      const int row = w * 32 + j * 8 + rA;  // row&7 == rA
      stage16(A + (unsigned)(m0 + row) * 1024 + k0 + ((cA ^ rA) * 8),
              &As[b][row * 64 + cA * 8]);
      stage16(Bt + (unsigned)(n0 + row) * 1024 + k0 + ((cA ^ rA) * 8),
              &Bs[b][row * 64 + cA * 8]);
    }
  };

  STAGE(0, 0);
  __syncthreads();

  int cur = 0;
  for (int k0 = 0; k0 < 1024; k0 += 64) {
    if (k0 < 960) STAGE(cur ^ 1, k0 + 64);  // issue early; drains at barrier

#pragma unroll
    for (int ks = 0; ks < 2; ks++) {
      short8 af[4], bf[4];
#pragma unroll
      for (int mi = 0; mi < 4; mi++) {
        int row = wm * 64 + mi * 16 + col;
        af[mi] = *(const short8*)&As[cur][row * 64 + (((ks * 4 + quad) ^ (col & 7)) * 8)];
      }
#pragma unroll
      for (int ni = 0; ni < 4; ni++) {
        int row = wn * 64 + ni * 16 + col;
        bf[ni] = *(const short8*)&Bs[cur][row * 64 + (((ks * 4 + quad) ^ (col & 7)) * 8)];
      }
#pragma unroll
      for (int mi = 0; mi < 4; mi++)
#pragma unroll
        for (int ni = 0; ni < 4; ni++) {
          if (SWAP)
            acc[ni][mi] = __builtin_amdgcn_mfma_f32_16x16x32_bf16(
                bf[ni], af[mi], acc[ni][mi], 0, 0, 0);
          else
            acc[mi][ni] = __builtin_amdgcn_mfma_f32_16x16x32_bf16(
                af[mi], bf[ni], acc[mi][ni], 0, 0, 0);
        }
    }

    __syncthreads();  // drains staged loads for k0+64; guards buffer reuse
    cur ^= 1;
  }

  if (MODE == 0) {  // SWAP: rows(quad*4+r)=hidden, cols(lane)=token
#pragma unroll
    for (int ni = 0; ni < 4; ni++) {
      const int cg = n0 + wn * 64 + ni * 16 + quad * 4;
      const int h = cg >> 6, dlo = cg & 63;
#pragma unroll
      for (int mi = 0; mi < 4; mi++) {
        const int tok = m0 + wm * 64 + mi * 16 + col;
        const int b = tok >> 11, s = tok & 2047;
        uint2 pk;
        pk.x = pk2f(acc[ni][mi][0], acc[ni][mi][1]);
        pk.y = pk2f(acc[ni][mi][2], acc[ni][mi][3]);
        *(uint2*)((unsigned short*)Cg +
                  ((unsigned)((b * 16 + h) * 2048 + s) * 64 + dlo)) = pk;
      }
    }
  } else if (MODE == 1) {  // rows(quad*4+r)=token(consec s), cols(lane)=hidden
#pragma unroll
    for (int mi = 0; mi < 4; mi++) {
      const int tok = m0 + wm * 64 + mi * 16 + quad * 4;
      const int b = tok >> 11, s = tok & 2047;
#pragma unroll
      for (int ni = 0; ni < 4; ni++) {
        const int cg = n0 + wn * 64 + ni * 16 + col;
        const int h = cg >> 6, d = cg & 63;
        uint2 pk;
        pk.x = pk2f(acc[mi][ni][0], acc[mi][ni][1]);
        pk.y = pk2f(acc[mi][ni][2], acc[mi][ni][3]);
        *(uint2*)((unsigned short*)Cg +
                  ((unsigned)((b * 16 + h) * 64 + d) * 2048 + s)) = pk;
      }
    }
  } else {  // fp32 [tok][1024], coalesced
#pragma unroll
    for (int mi = 0; mi < 4; mi++) {
      const int row = m0 + wm * 64 + mi * 16 + quad * 4;
#pragma unroll
      for (int ni = 0; ni < 4; ni++) {
        const int cg = n0 + wn * 64 + ni * 16 + col;
#pragma unroll
        for (int r = 0; r < 4; r++)
          ((float*)Cg)[(unsigned)(row + r) * 1024 + cg] = acc[mi][ni][r];
      }
    }
  }
}

// ---------------- attention (32x32 swapped, in-register softmax) ----------------
// Grid = 1024 linear blocks; swizzle puts the 16 q-blocks of a head on one XCD
// (K/V stream served from L2). 4 waves x 32 q-rows = 128 q / block; KVBLK=64.
// Streaming softmax (no max subtraction), Q pre-scaled by log2e/8 so
// P = exp2(K@Q^T). Per KV tile:
//   S^T[k][q] = mfma_32x32x16(K_frag, Q_frag): lane holds q=lane&31, 16 k-rows
//     per t at row = (r&3)+8*(r>>2)+4*hi  [verified C/D layout]
//   P -> bf16 B-fragments IN REGISTER: v_cvt_pk_bf16_f32 + permlane32_swap
//     (swap(P0,P2) -> words 0,2; swap(P1,P3) -> words 1,3)
//   O^T[d][q] += mfma_32x32x16(V^T_frag, P_frag): C cols = q -> den scale is
//     lane-local; rows = d in packable quads.
//   den[q] += mfma_32x32x16(ones, P_frag): 1^T@P on the MFMA pipe; C/D layout
//     puts den[q] in every lane's dacc[0] -> no cross-lane reduce, no VALU adds.
// K_lds/V_lds double-buffered, stage(kt+1) issued before compute(kt),
// single __syncthreads per tile (vmcnt drain covers staged loads).
__global__ __launch_bounds__(256, 4) void attn_kernel(
    const unsigned short* __restrict__ Qb, const unsigned short* __restrict__ Kb,
    const unsigned short* __restrict__ Vt, unsigned short* __restrict__ Ob) {
  __shared__ __align__(16) unsigned short K_lds[2][64 * 64];  // [s][d] sw8
  __shared__ __align__(16) unsigned short V_lds[2][64 * 64];  // [d][s] sw8

  const int tid = threadIdx.x;
  const int lane = tid & 63;
  const int w = tid >> 6;
  const int l5 = lane & 31, hi = lane >> 5;

  // swizzle: bh = ((lin>>3)&7)*8 + (lin&7), qt = lin>>6  (16 q-tiles of 128)
  const int lin = blockIdx.x;
  const int bh = ((lin >> 3) & 7) * 8 + (lin & 7);
  const int qt = lin >> 6;

  const unsigned short* Kbase = Kb + (size_t)bh * (2048 * 64);
  const unsigned short* Vbase = Vt + (size_t)bh * (64 * 2048);
  const int q0 = qt * 128 + w * 32;

  // Q B-fragments (held in regs): lane q = l5, d = c*16 + hi*8 + j
  short8 qf[4];
#pragma unroll
  for (int c = 0; c < 4; c++)
    qf[c] = *(const short8*)(Qb + ((size_t)bh * 2048 + q0 + l5) * 64 + c * 16 + hi * 8);

  // ones A-fragment for the denominator MFMA (bf16 1.0 = 0x3F80)
  short8 onef;
#pragma unroll
  for (int j = 0; j < 8; j++) onef[j] = (short)0x3F80;

  float16v oacc[2] = {};  // O^T tiles: [dt] rows=d-local, cols=q
  float16v dacc = {};     // den[q] (all 16 rows identical)

  const int sr = lane >> 3, sc = lane & 7;

  // stage K/V tile kt into buffer b: row&7 == sr -> swizzle chunk = sc^sr.
  // LDS dest is lane-linear (base + lane*16B) as global_load_lds requires.
  auto STAGE = [&](int b, int kt) {
    const int s0 = kt * 64;
#pragma unroll
    for (int j = 0; j < 2; j++) {
      const int row = w * 16 + j * 8 + sr;
      stage16(Kbase + (unsigned)(s0 + row) * 64 + ((sc ^ sr) * 8),
              &K_lds[b][row * 64 + sc * 8]);
      stage16(Vbase + (unsigned)row * 2048 + s0 + ((sc ^ sr) * 8),
              &V_lds[b][row * 64 + sc * 8]);
    }
  };

  STAGE(0, 0);
  __syncthreads();

  int cur = 0;
  for (int kt = 0; kt < 32; kt++) {
    if (kt < 31) STAGE(cur ^ 1, kt + 1);  // issue early; drains at barrier

    const unsigned short* Kl = &K_lds[cur][0];
    const unsigned short* Vl = &V_lds[cur][0];

    short8 pf[4];  // pf[kc]: B[k = kc*16 + hi*8 + j][q = l5]
#pragma unroll
    for (int t = 0; t < 2; t++) {
      // --- S^T = K @ Q^T for this 32-k slab ---
      float16v sacc = {};
      __builtin_amdgcn_s_setprio(1);
#pragma unroll
      for (int c = 0; c < 4; c++) {
        short8 kf = *(const short8*)&Kl[(t * 32 + l5) * 64 +
                                        (((c * 2 + hi) ^ (l5 & 7)) * 8)];
        sacc = __builtin_amdgcn_mfma_f32_32x32x16_bf16(kf, qf[c], sacc, 0, 0, 0);
      }
      __builtin_amdgcn_s_setprio(0);

      // --- P = exp2(S^T); cvt_pk + permlane into PV B-fragments ---
#pragma unroll
      for (int half = 0; half < 2; half++) {
        const int k0 = half * 8;
        unsigned P0 = cvtpk(EXP2F(sacc[k0 + 0]), EXP2F(sacc[k0 + 1]));
        unsigned P1 = cvtpk(EXP2F(sacc[k0 + 2]), EXP2F(sacc[k0 + 3]));
        unsigned P2 = cvtpk(EXP2F(sacc[k0 + 4]), EXP2F(sacc[k0 + 5]));
        unsigned P3 = cvtpk(EXP2F(sacc[k0 + 6]), EXP2F(sacc[k0 + 7]));
        unsigned u0, u1, u2, u3;
#if __has_builtin(__builtin_amdgcn_permlane32_swap)
        uint2v a02 = __builtin_amdgcn_permlane32_swap(P0, P2, false, false);
        uint2v a13 = __builtin_amdgcn_permlane32_swap(P1, P3, false, false);
        u0 = a02[0]; u2 = a02[1];
        u1 = a13[0]; u3 = a13[1];
#else
        unsigned p0s = __shfl_xor((int)P0, 32), p2s = __shfl_xor((int)P2, 32);
        unsigned p1s = __shfl_xor((int)P1, 32), p3s = __shfl_xor((int)P3, 32);
        u0 = hi ? p2s : P0; u2 = hi ? P2 : p0s;
        u1 = hi ? p3s : P1; u3 = hi ? P3 : p1s;
#endif
        union { unsigned u[4]; short8 s; } cv;
        cv.u[0] = u0; cv.u[1] = u1; cv.u[2] = u2; cv.u[3] = u3;
        pf[t * 2 + half] = cv.s;
      }
    }

    // --- O^T += V^T @ P (2 d-tiles x 4 k-chunks) and den += 1^T @ P ---
    __builtin_amdgcn_s_setprio(1);
#pragma unroll
    for (int dt = 0; dt < 2; dt++)
#pragma unroll
      for (int kc = 0; kc < 4; kc++) {
        short8 vf = *(const short8*)&Vl[(dt * 32 + l5) * 64 +
                                        (((kc * 2 + hi) ^ (l5 & 7)) * 8)];
        oacc[dt] = __builtin_amdgcn_mfma_f32_32x32x16_bf16(vf, pf[kc], oacc[dt], 0, 0, 0);
      }
#pragma unroll
    for (int kc = 0; kc < 4; kc++)
      dacc = __builtin_amdgcn_mfma_f32_32x32x16_bf16(onef, pf[kc], dacc, 0, 0, 0);
    __builtin_amdgcn_s_setprio(0);

    __syncthreads();  // drains staged loads for kt+1; guards buffer reuse
    cur ^= 1;
  }

  // --- dacc rows all identical = den[q=l5]; lane-local reciprocal ---
  const float rd = 1.f / dacc[0];

  // --- O / den -> Ob [B][S][1024] bf16; reg quads = 4 consecutive d ---
  const int b = bh >> 4, h = bh & 15;
  const unsigned obase = (unsigned)(b * 2048 + q0 + l5) * 1024 + h * 64;
#pragma unroll
  for (int dt = 0; dt < 2; dt++)
#pragma unroll
    for (int g = 0; g < 4; g++) {
      uint2 pk;
      pk.x = cvtpk(oacc[dt][4 * g + 0] * rd, oacc[dt][4 * g + 1] * rd);
      pk.y = cvtpk(oacc[dt][4 * g + 2] * rd, oacc[dt][4 * g + 3] * rd);
      *(uint2*)(Ob + obase + dt * 32 + 8 * g + 4 * hi) = pk;
    }
}

extern "C" void kernel_launch(void* const* d_in, const int* in_sizes, int n_in,
                              void* d_out, int out_size, void* d_ws, size_t ws_size,
                              hipStream_t stream) {
  const float* q = (const float*)d_in[0];
  const float* k = (const float*)d_in[1];
  const float* v = (const float*)d_in[2];
  const float* Wq = (const float*)d_in[3];
  const float* Wk = (const float*)d_in[4];
  const float* Wv = (const float*)d_in[5];
  const float* Wo = (const float*)d_in[6];

  unsigned short* ws = (unsigned short*)d_ws;
  unsigned short* qb = ws;  // reused as Ob after attention
  unsigned short* kb = ws + 8388608;
  unsigned short* vb = ws + 16777216;
  unsigned short* Qb = ws + 25165824;
  unsigned short* Kb = ws + 33554432;
  unsigned short* Vt = ws + 41943040;
  unsigned short* Wt = ws + 50331648;

  dim3 blk(256);
  const float qscale = 0.18033688011112042f;  // log2(e) / sqrt(64)

  conv_qkv<<<dim3(4096, 3), blk, 0, stream>>>(q, k, v, ws, qscale);
  wtrans<<<dim3(32, 32, 4), blk, 0, stream>>>(Wq, Wk, Wv, Wo, Wt);

  gemm_bt<0, true><<<dim3(512), blk, 0, stream>>>(qb, Wt + 0 * 1048576, Qb);
  gemm_bt<0, true><<<dim3(512), blk, 0, stream>>>(kb, Wt + 1 * 1048576, Kb);
  gemm_bt<1, false><<<dim3(512), blk, 0, stream>>>(vb, Wt + 2 * 1048576, Vt);

  attn_kernel<<<dim3(1024), blk, 0, stream>>>(Qb, Kb, Vt, qb /*Ob*/);

  gemm_bt<2, false><<<dim3(512), blk, 0, stream>>>(qb /*Ob*/, Wt + 3 * 1048576,
                                                   (float*)d_out);
}

// Round 4
// 323.057 us; speedup vs baseline: 1.0620x; 1.0505x over previous
//
#include <hip/hip_runtime.h>

// MHA: B=4, S=2048, HID=1024, H=16, D=64. fp32 in/out, bf16 MFMA internally.
// R8: GEMM restructure for occupancy + observability.
//   - 3 QKV GEMMs merged into ONE 1536-block dispatch (gemm_qkv): no
//     inter-GEMM serialization/tails, 6 blocks/CU of work in flight,
//     and the GEMM cost becomes directly visible in rocprof top-5.
//   - BK 64->32: LDS 64->32KB per block -> __launch_bounds__(256,4) ->
//     4 blocks/CU resident (16 waves, 2x TLP for latency hiding).
//     Double-XOR LDS swizzle (quad ^ row&3 ^ (row>>2)&3) = balanced
//     2-lanes-per-bank-class (free 2-way) on ds_read_b128.
//   - attn unchanged from R6 (87.7us, MfmaUtil 44%).
//
// ws layout (u16 elems):
//   qb/Ob : 0         (converted q, scaled by log2e/8; reused for attn out)
//   kb    : 8388608
//   vb    : 16777216
//   Qb    : 25165824  [BH][S][64]
//   Kb    : 33554432  [BH][S][64]
//   Vt    : 41943040  [BH][64][S]
//   Wt    : 50331648  4x [N=1024][K=1024] bf16 (Wq,Wk,Wv,Wo transposed)

typedef __attribute__((ext_vector_type(8))) short short8;
typedef __attribute__((ext_vector_type(4))) float float4v;
typedef __attribute__((ext_vector_type(16))) float float16v;
typedef __attribute__((ext_vector_type(2))) unsigned int uint2v;

#if __has_builtin(__builtin_amdgcn_exp2f)
#define EXP2F(x) __builtin_amdgcn_exp2f(x)
#else
#define EXP2F(x) exp2f(x)
#endif

// round-half-up bf16 (tie-only deviation from RNE, <=1 ulp): 2 ops
__device__ __forceinline__ unsigned short f2b(float x) {
  return (unsigned short)((__float_as_uint(x) + 0x8000u) >> 16);
}
// pack two floats -> two bf16 in 3 VALU (add, add, v_perm). low16 = a.
__device__ __forceinline__ unsigned pk2f(float a, float b) {
  unsigned ua = __float_as_uint(a) + 0x8000u;
  unsigned ub = __float_as_uint(b) + 0x8000u;
  return __builtin_amdgcn_perm(ub, ua, 0x07060302);
}
// pack two floats -> two bf16 in ONE VALU (RNE). low16 = a.
__device__ __forceinline__ unsigned cvtpk(float a, float b) {
  unsigned r;
  asm("v_cvt_pk_bf16_f32 %0, %1, %2" : "=v"(r) : "v"(a), "v"(b));
  return r;
}

// async global->LDS, 16B per lane (dest = wave-uniform base + lane*16).
typedef __attribute__((address_space(3))) unsigned int lds_uint;
typedef const __attribute__((address_space(1))) unsigned int gbl_uint;
__device__ __forceinline__ void stage16(const unsigned short* g, unsigned short* l) {
#if __has_builtin(__builtin_amdgcn_global_load_lds)
  __builtin_amdgcn_global_load_lds((gbl_uint*)g, (lds_uint*)l, 16, 0, 0);
#else
  *(uint4*)l = *(const uint4*)g;
#endif
}

// ---------------- conversion kernels ----------------
__global__ __launch_bounds__(256) void conv_qkv(const float* __restrict__ q,
                                                const float* __restrict__ k,
                                                const float* __restrict__ v,
                                                unsigned short* __restrict__ ws,
                                                float qscale) {
  const int z = blockIdx.y;
  const float* src = z == 0 ? q : (z == 1 ? k : v);
  unsigned short* dst = ws + (size_t)z * 8388608;
  const float s = z == 0 ? qscale : 1.0f;
  size_t i = ((size_t)blockIdx.x * 256 + threadIdx.x) * 8;
  float4v a = *(const float4v*)(src + i);
  float4v b = *(const float4v*)(src + i + 4);
  uint4 o;
  o.x = pk2f(a.x * s, a.y * s);
  o.y = pk2f(a.z * s, a.w * s);
  o.z = pk2f(b.x * s, b.y * s);
  o.w = pk2f(b.z * s, b.w * s);
  *(uint4*)(dst + i) = o;
}

// W [K][N] fp32 -> Wt [N][K] bf16, LDS 32x33 tile transpose. 4 matrices (z).
__global__ __launch_bounds__(256) void wtrans(const float* __restrict__ Wq,
                                              const float* __restrict__ Wk,
                                              const float* __restrict__ Wv,
                                              const float* __restrict__ Wo,
                                              unsigned short* __restrict__ Wt) {
  __shared__ float tile[32][33];
  const float* W = blockIdx.z == 0 ? Wq : blockIdx.z == 1 ? Wk
                   : blockIdx.z == 2 ? Wv : Wo;
  unsigned short* T = Wt + (size_t)blockIdx.z * 1048576;
  const int tx = threadIdx.x & 31, ty = threadIdx.x >> 5;
  const int k0 = blockIdx.y * 32, n0 = blockIdx.x * 32;
#pragma unroll
  for (int i = 0; i < 4; i++)
    tile[ty + 8 * i][tx] = W[(size_t)(k0 + ty + 8 * i) * 1024 + n0 + tx];
  __syncthreads();
#pragma unroll
  for (int i = 0; i < 4; i++)
    T[(size_t)(n0 + ty + 8 * i) * 1024 + k0 + tx] = f2b(tile[tx][ty + 8 * i]);
}

// ---------------- GEMM core: C = A(8192x1024) @ Bt^T, bf16, BK=32 ----------------
// 512 tiles of 128x128. XCD swizzle: A-tile(m) sharers co-XCD for L2 reuse.
// Stage-early double-buffer: STAGE(k0+32) issued before compute(k0), one
// __syncthreads per K-step. LDS 32KB -> 4 blocks/CU.
// LDS swizzle: slot = chunk ^ (row&3) ^ ((row>>2)&3) (applied inverse on the
// global source; LDS dest lane-linear as global_load_lds requires). Fragment
// ds_read_b128 then hits each 128B bank-class with exactly 2 lanes (free).
// MODE 0 (SWAP): bf16 out [(b*16+h)*2048+s][64]; MODE 1: bf16 [(bh)*64+d][2048]
// (V^T); MODE 2: fp32 [tok][1024].
template <int MODE, bool SWAP>
__device__ __forceinline__ void gemm_core(const unsigned short* __restrict__ A,
                                          const unsigned short* __restrict__ Bt,
                                          void* __restrict__ Cg, int lin,
                                          unsigned short (*__restrict__ As)[128 * 32],
                                          unsigned short (*__restrict__ Bs)[128 * 32]) {
  const int tid = threadIdx.x;
  const int lane = tid & 63;
  const int w = tid >> 6;
  const int quad = lane >> 4, col = lane & 15;
  const int wm = w >> 1, wn = w & 1;
  // XCD swizzle: m_tile = (grp&7)*8 + xcd; n_tile = grp>>3
  const int xcd = lin & 7, grp = lin >> 3;
  const int m0 = ((grp & 7) * 8 + xcd) * 128;
  const int n0 = (grp >> 3) * 128;

  // staging indices: thread covers 16B chunk schunk of row srow (+64*j)
  const int srow = tid >> 2, schunk = tid & 3;
  const int sg = schunk ^ (srow & 3) ^ ((srow >> 2) & 3);  // global chunk held

  float4v acc[4][4] = {};  // SWAP: [ni][mi]; else [mi][ni]

  auto STAGE = [&](int b, int k0) {
#pragma unroll
    for (int j = 0; j < 2; j++) {
      const int row = j * 64 + srow;  // (row>>2)&3 invariant in j (64/4 = 16)
      stage16(A + (unsigned)(m0 + row) * 1024 + k0 + sg * 8,
              &As[b][row * 32 + schunk * 8]);
      stage16(Bt + (unsigned)(n0 + row) * 1024 + k0 + sg * 8,
              &Bs[b][row * 32 + schunk * 8]);
    }
  };

  STAGE(0, 0);
  __syncthreads();

  int cur = 0;
  for (int k0 = 0; k0 < 1024; k0 += 32) {
    if (k0 < 992) STAGE(cur ^ 1, k0 + 32);  // issue early; drains at barrier

    short8 af[4], bf[4];
#pragma unroll
    for (int mi = 0; mi < 4; mi++) {
      const int row = wm * 64 + mi * 16 + col;
      af[mi] = *(const short8*)&As[cur][row * 32 +
                                        ((quad ^ (row & 3) ^ ((row >> 2) & 3)) * 8)];
    }
#pragma unroll
    for (int ni = 0; ni < 4; ni++) {
      const int row = wn * 64 + ni * 16 + col;
      bf[ni] = *(const short8*)&Bs[cur][row * 32 +
                                        ((quad ^ (row & 3) ^ ((row >> 2) & 3)) * 8)];
    }
#pragma unroll
    for (int mi = 0; mi < 4; mi++)
#pragma unroll
      for (int ni = 0; ni < 4; ni++) {
        if (SWAP)
          acc[ni][mi] = __builtin_amdgcn_mfma_f32_16x16x32_bf16(
              bf[ni], af[mi], acc[ni][mi], 0, 0, 0);
        else
          acc[mi][ni] = __builtin_amdgcn_mfma_f32_16x16x32_bf16(
              af[mi], bf[ni], acc[mi][ni], 0, 0, 0);
      }

    __syncthreads();  // drains staged loads for k0+32; guards buffer reuse
    cur ^= 1;
  }

  if (MODE == 0) {  // SWAP: rows(quad*4+r)=hidden, cols(lane)=token
#pragma unroll
    for (int ni = 0; ni < 4; ni++) {
      const int cg = n0 + wn * 64 + ni * 16 + quad * 4;
      const int h = cg >> 6, dlo = cg & 63;
#pragma unroll
      for (int mi = 0; mi < 4; mi++) {
        const int tok = m0 + wm * 64 + mi * 16 + col;
        const int b = tok >> 11, s = tok & 2047;
        uint2 pk;
        pk.x = pk2f(acc[ni][mi][0], acc[ni][mi][1]);
        pk.y = pk2f(acc[ni][mi][2], acc[ni][mi][3]);
        *(uint2*)((unsigned short*)Cg +
                  ((unsigned)((b * 16 + h) * 2048 + s) * 64 + dlo)) = pk;
      }
    }
  } else if (MODE == 1) {  // rows(quad*4+r)=token(consec s), cols(lane)=hidden
#pragma unroll
    for (int mi = 0; mi < 4; mi++) {
      const int tok = m0 + wm * 64 + mi * 16 + quad * 4;
      const int b = tok >> 11, s = tok & 2047;
#pragma unroll
      for (int ni = 0; ni < 4; ni++) {
        const int cg = n0 + wn * 64 + ni * 16 + col;
        const int h = cg >> 6, d = cg & 63;
        uint2 pk;
        pk.x = pk2f(acc[mi][ni][0], acc[mi][ni][1]);
        pk.y = pk2f(acc[mi][ni][2], acc[mi][ni][3]);
        *(uint2*)((unsigned short*)Cg +
                  ((unsigned)((b * 16 + h) * 64 + d) * 2048 + s)) = pk;
      }
    }
  } else {  // fp32 [tok][1024], coalesced
#pragma unroll
    for (int mi = 0; mi < 4; mi++) {
      const int row = m0 + wm * 64 + mi * 16 + quad * 4;
#pragma unroll
      for (int ni = 0; ni < 4; ni++) {
        const int cg = n0 + wn * 64 + ni * 16 + col;
#pragma unroll
        for (int r = 0; r < 4; r++)
          ((float*)Cg)[(unsigned)(row + r) * 1024 + cg] = acc[mi][ni][r];
      }
    }
  }
}

// merged QKV projections: z = block/512 selects {q,k,v} x {Wq,Wk,Wv} x out.
// act/out sub-buffers are contiguous at stride 8388608; Wt at 1048576.
__global__ __launch_bounds__(256, 4) void gemm_qkv(const unsigned short* __restrict__ act,
                                                   const unsigned short* __restrict__ Wt,
                                                   unsigned short* __restrict__ out) {
  __shared__ __align__(16) unsigned short As[2][128 * 32];
  __shared__ __align__(16) unsigned short Bs[2][128 * 32];
  const int z = blockIdx.x >> 9, r = blockIdx.x & 511;
  if (z < 2)  // Q, K: MODE 0, swapped operands
    gemm_core<0, true>(act + (size_t)z * 8388608, Wt + (size_t)z * 1048576,
                       out + (size_t)z * 8388608, r, As, Bs);
  else  // V: MODE 1 (V^T layout)
    gemm_core<1, false>(act + (size_t)2 * 8388608, Wt + (size_t)2 * 1048576,
                        out + (size_t)2 * 8388608, r, As, Bs);
}

template <int MODE, bool SWAP>
__global__ __launch_bounds__(256, 4) void gemm_bt(const unsigned short* __restrict__ A,
                                                  const unsigned short* __restrict__ Bt,
                                                  void* __restrict__ Cg) {
  __shared__ __align__(16) unsigned short As[2][128 * 32];
  __shared__ __align__(16) unsigned short Bs[2][128 * 32];
  gemm_core<MODE, SWAP>(A, Bt, Cg, blockIdx.x, As, Bs);
}

// ---------------- attention (32x32 swapped, in-register softmax) ----------------
// Grid = 1024 linear blocks; swizzle puts the 16 q-blocks of a head on one XCD
// (K/V stream served from L2). 4 waves x 32 q-rows = 128 q / block; KVBLK=64.
// Streaming softmax (no max subtraction), Q pre-scaled by log2e/8 so
// P = exp2(K@Q^T). Per KV tile:
//   S^T[k][q] = mfma_32x32x16(K_frag, Q_frag): lane holds q=lane&31, 16 k-rows
//     per t at row = (r&3)+8*(r>>2)+4*hi  [verified C/D layout]
//   P -> bf16 B-fragments IN REGISTER: v_cvt_pk_bf16_f32 + permlane32_swap
//     (swap(P0,P2) -> words 0,2; swap(P1,P3) -> words 1,3)
//   O^T[d][q] += mfma_32x32x16(V^T_frag, P_frag): C cols = q -> den scale is
//     lane-local; rows = d in packable quads.
//   den[q] += mfma_32x32x16(ones, P_frag): 1^T@P on the MFMA pipe; C/D layout
//     puts den[q] in every lane's dacc[0] -> no cross-lane reduce, no VALU adds.
// K_lds/V_lds double-buffered, stage(kt+1) issued before compute(kt),
// single __syncthreads per tile (vmcnt drain covers staged loads).
__global__ __launch_bounds__(256, 4) void attn_kernel(
    const unsigned short* __restrict__ Qb, const unsigned short* __restrict__ Kb,
    const unsigned short* __restrict__ Vt, unsigned short* __restrict__ Ob) {
  __shared__ __align__(16) unsigned short K_lds[2][64 * 64];  // [s][d] sw8
  __shared__ __align__(16) unsigned short V_lds[2][64 * 64];  // [d][s] sw8

  const int tid = threadIdx.x;
  const int lane = tid & 63;
  const int w = tid >> 6;
  const int l5 = lane & 31, hi = lane >> 5;

  // swizzle: bh = ((lin>>3)&7)*8 + (lin&7), qt = lin>>6  (16 q-tiles of 128)
  const int lin = blockIdx.x;
  const int bh = ((lin >> 3) & 7) * 8 + (lin & 7);
  const int qt = lin >> 6;

  const unsigned short* Kbase = Kb + (size_t)bh * (2048 * 64);
  const unsigned short* Vbase = Vt + (size_t)bh * (64 * 2048);
  const int q0 = qt * 128 + w * 32;

  // Q B-fragments (held in regs): lane q = l5, d = c*16 + hi*8 + j
  short8 qf[4];
#pragma unroll
  for (int c = 0; c < 4; c++)
    qf[c] = *(const short8*)(Qb + ((size_t)bh * 2048 + q0 + l5) * 64 + c * 16 + hi * 8);

  // ones A-fragment for the denominator MFMA (bf16 1.0 = 0x3F80)
  short8 onef;
#pragma unroll
  for (int j = 0; j < 8; j++) onef[j] = (short)0x3F80;

  float16v oacc[2] = {};  // O^T tiles: [dt] rows=d-local, cols=q
  float16v dacc = {};     // den[q] (all 16 rows identical)

  const int sr = lane >> 3, sc = lane & 7;

  // stage K/V tile kt into buffer b: row&7 == sr -> swizzle chunk = sc^sr.
  // LDS dest is lane-linear (base + lane*16B) as global_load_lds requires.
  auto STAGE = [&](int b, int kt) {
    const int s0 = kt * 64;
#pragma unroll
    for (int j = 0; j < 2; j++) {
      const int row = w * 16 + j * 8 + sr;
      stage16(Kbase + (unsigned)(s0 + row) * 64 + ((sc ^ sr) * 8),
              &K_lds[b][row * 64 + sc * 8]);
      stage16(Vbase + (unsigned)row * 2048 + s0 + ((sc ^ sr) * 8),
              &V_lds[b][row * 64 + sc * 8]);
    }
  };

  STAGE(0, 0);
  __syncthreads();

  int cur = 0;
  for (int kt = 0; kt < 32; kt++) {
    if (kt < 31) STAGE(cur ^ 1, kt + 1);  // issue early; drains at barrier

    const unsigned short* Kl = &K_lds[cur][0];
    const unsigned short* Vl = &V_lds[cur][0];

    short8 pf[4];  // pf[kc]: B[k = kc*16 + hi*8 + j][q = l5]
#pragma unroll
    for (int t = 0; t < 2; t++) {
      // --- S^T = K @ Q^T for this 32-k slab ---
      float16v sacc = {};
      __builtin_amdgcn_s_setprio(1);
#pragma unroll
      for (int c = 0; c < 4; c++) {
        short8 kf = *(const short8*)&Kl[(t * 32 + l5) * 64 +
                                        (((c * 2 + hi) ^ (l5 & 7)) * 8)];
        sacc = __builtin_amdgcn_mfma_f32_32x32x16_bf16(kf, qf[c], sacc, 0, 0, 0);
      }
      __builtin_amdgcn_s_setprio(0);

      // --- P = exp2(S^T); cvt_pk + permlane into PV B-fragments ---
#pragma unroll
      for (int half = 0; half < 2; half++) {
        const int k0 = half * 8;
        unsigned P0 = cvtpk(EXP2F(sacc[k0 + 0]), EXP2F(sacc[k0 + 1]));
        unsigned P1 = cvtpk(EXP2F(sacc[k0 + 2]), EXP2F(sacc[k0 + 3]));
        unsigned P2 = cvtpk(EXP2F(sacc[k0 + 4]), EXP2F(sacc[k0 + 5]));
        unsigned P3 = cvtpk(EXP2F(sacc[k0 + 6]), EXP2F(sacc[k0 + 7]));
        unsigned u0, u1, u2, u3;
#if __has_builtin(__builtin_amdgcn_permlane32_swap)
        uint2v a02 = __builtin_amdgcn_permlane32_swap(P0, P2, false, false);
        uint2v a13 = __builtin_amdgcn_permlane32_swap(P1, P3, false, false);
        u0 = a02[0]; u2 = a02[1];
        u1 = a13[0]; u3 = a13[1];
#else
        unsigned p0s = __shfl_xor((int)P0, 32), p2s = __shfl_xor((int)P2, 32);
        unsigned p1s = __shfl_xor((int)P1, 32), p3s = __shfl_xor((int)P3, 32);
        u0 = hi ? p2s : P0; u2 = hi ? P2 : p0s;
        u1 = hi ? p3s : P1; u3 = hi ? P3 : p1s;
#endif
        union { unsigned u[4]; short8 s; } cv;
        cv.u[0] = u0; cv.u[1] = u1; cv.u[2] = u2; cv.u[3] = u3;
        pf[t * 2 + half] = cv.s;
      }
    }

    // --- O^T += V^T @ P (2 d-tiles x 4 k-chunks) and den += 1^T @ P ---
    __builtin_amdgcn_s_setprio(1);
#pragma unroll
    for (int dt = 0; dt < 2; dt++)
#pragma unroll
      for (int kc = 0; kc < 4; kc++) {
        short8 vf = *(const short8*)&Vl[(dt * 32 + l5) * 64 +
                                        (((kc * 2 + hi) ^ (l5 & 7)) * 8)];
        oacc[dt] = __builtin_amdgcn_mfma_f32_32x32x16_bf16(vf, pf[kc], oacc[dt], 0, 0, 0);
      }
#pragma unroll
    for (int kc = 0; kc < 4; kc++)
      dacc = __builtin_amdgcn_mfma_f32_32x32x16_bf16(onef, pf[kc], dacc, 0, 0, 0);
    __builtin_amdgcn_s_setprio(0);

    __syncthreads();  // drains staged loads for kt+1; guards buffer reuse
    cur ^= 1;
  }

  // --- dacc rows all identical = den[q=l5]; lane-local reciprocal ---
  const float rd = 1.f / dacc[0];

  // --- O / den -> Ob [B][S][1024] bf16; reg quads = 4 consecutive d ---
  const int b = bh >> 4, h = bh & 15;
  const unsigned obase = (unsigned)(b * 2048 + q0 + l5) * 1024 + h * 64;
#pragma unroll
  for (int dt = 0; dt < 2; dt++)
#pragma unroll
    for (int g = 0; g < 4; g++) {
      uint2 pk;
      pk.x = cvtpk(oacc[dt][4 * g + 0] * rd, oacc[dt][4 * g + 1] * rd);
      pk.y = cvtpk(oacc[dt][4 * g + 2] * rd, oacc[dt][4 * g + 3] * rd);
      *(uint2*)(Ob + obase + dt * 32 + 8 * g + 4 * hi) = pk;
    }
}

extern "C" void kernel_launch(void* const* d_in, const int* in_sizes, int n_in,
                              void* d_out, int out_size, void* d_ws, size_t ws_size,
                              hipStream_t stream) {
  const float* q = (const float*)d_in[0];
  const float* k = (const float*)d_in[1];
  const float* v = (const float*)d_in[2];
  const float* Wq = (const float*)d_in[3];
  const float* Wk = (const float*)d_in[4];
  const float* Wv = (const float*)d_in[5];
  const float* Wo = (const float*)d_in[6];

  unsigned short* ws = (unsigned short*)d_ws;
  unsigned short* qb = ws;  // reused as Ob after attention
  unsigned short* Qb = ws + 25165824;
  unsigned short* Kb = ws + 33554432;
  unsigned short* Vt = ws + 41943040;
  unsigned short* Wt = ws + 50331648;

  dim3 blk(256);
  const float qscale = 0.18033688011112042f;  // log2(e) / sqrt(64)

  conv_qkv<<<dim3(4096, 3), blk, 0, stream>>>(q, k, v, ws, qscale);
  wtrans<<<dim3(32, 32, 4), blk, 0, stream>>>(Wq, Wk, Wv, Wo, Wt);

  gemm_qkv<<<dim3(1536), blk, 0, stream>>>(ws, Wt, Qb);

  attn_kernel<<<dim3(1024), blk, 0, stream>>>(Qb, Kb, Vt, qb /*Ob*/);

  gemm_bt<2, false><<<dim3(512), blk, 0, stream>>>(qb /*Ob*/, Wt + 3 * 1048576,
                                                   (float*)d_out);
}